// Round 4
// baseline (255.209 us; speedup 1.0000x reference)
//
#include <hip/hip_runtime.h>

typedef _Float16 f16;
typedef __attribute__((ext_vector_type(4))) _Float16 f16x4;
typedef __attribute__((ext_vector_type(8))) _Float16 f16x8;
typedef __attribute__((ext_vector_type(4))) float f32x4;

#define NB 2
#define NS 2048
#define NHID 2048
#define N_H 16
#define N_KV 4
#define N_HD 128

__device__ __forceinline__ void gload16(void* lds, const void* g) {
  __builtin_amdgcn_global_load_lds(
      (const __attribute__((address_space(1))) unsigned int*)g,
      (__attribute__((address_space(3))) unsigned int*)lds, 16, 0, 0);
}

// ---------------- f32 -> f16 convert (vectorized) ----------------
__global__ __launch_bounds__(256) void cvt_kernel(const float* __restrict__ in,
                                                  f16* __restrict__ out, int n4) {
  int i = blockIdx.x * 256 + threadIdx.x;
  if (i >= n4) return;
  const float4 v = reinterpret_cast<const float4*>(in)[i];
  f16x4 o = {(f16)v.x, (f16)v.y, (f16)v.z, (f16)v.w};
  reinterpret_cast<f16x4*>(out)[i] = o;
}

// 3-source convert into one contiguous dest (Wq|Wk|Wv)
__global__ __launch_bounds__(256) void cvt3_kernel(const float* __restrict__ a, int na4,
                                                   const float* __restrict__ b, int nb4,
                                                   const float* __restrict__ c, int nc4,
                                                   f16* __restrict__ out) {
  int i = blockIdx.x * 256 + threadIdx.x;
  if (i >= na4 + nb4 + nc4) return;
  const float* src;
  int j;
  if (i < na4) { src = a; j = i; }
  else if (i < na4 + nb4) { src = b; j = i - na4; }
  else { src = c; j = i - na4 - nb4; }
  const float4 v = reinterpret_cast<const float4*>(src)[j];
  f16x4 o = {(f16)v.x, (f16)v.y, (f16)v.z, (f16)v.w};
  reinterpret_cast<f16x4*>(out)[i] = o;
}

// ---------------- pipelined GEMM: C[M,N] = A[M,K] * B[N,K]^T ----------------
// BN=256, BM = MREP*32. 8 waves (2Mx4N), BK=32, 4-buffer ring, counted vmcnt.
// 1-D grid with XCD-rectangle swizzle: blocks on XCD x (= bid&7) cover a
// compact mb x nb rectangle so each XCD's L2 holds few A/B panels (T1).
// MODE 0 (QKV, grid 192 = 16mb x 12nb, rect 4x6): scatter Q/K/V fp16 [B,H,S,D].
// MODE 1 (outproj, grid 256 = 32mb x 8nb, rect 8x4): f32 out + bias.
template <int MREP, int MODE>
__global__ __launch_bounds__(512, 2) void gemm8(
    const f16* __restrict__ A, const f16* __restrict__ Bm, const int K,
    f16* __restrict__ q_out, f16* __restrict__ k_out, f16* __restrict__ v_out,
    float* __restrict__ f_out, const float* __restrict__ bias) {
  constexpr int BM = MREP * 32;
  constexpr int GA = BM / 128;             // A granules (8KB each)
  constexpr int G = GA + 2;                // granules per K-tile
  constexpr int NPH = (MREP == 8) ? 2 : 1; // phases per K-tile
  constexpr int ATILE = BM * 32;
  constexpr int BTILE = 256 * 32;
  constexpr int BUF = ATILE + BTILE;
  __shared__ f16 lds[4 * BUF];

  const int t = threadIdx.x;
  const int l = t & 63, w = t >> 6;
  const int g = l >> 4, l15 = l & 15;
  const int wr = w >> 2, wc = w & 3;  // 2 x 4 wave grid
  // XCD-rectangle swizzle
  const int orig = blockIdx.x;
  const int x = orig & 7, loc = orig >> 3;
  int mb, nb;
  if constexpr (MODE == 0) { mb = (x & 3) * 4 + (loc & 3); nb = (x >> 2) * 6 + (loc >> 2); }
  else                     { mb = (x & 3) * 8 + (loc & 7); nb = (x >> 2) * 4 + (loc >> 3); }
  const int NT = K >> 5;

  const f16* Aorig = A + (size_t)(mb * BM) * K;
  const f16* Borig = Bm + (size_t)(nb * 256) * K;

  // per-thread staging source offsets (f16 units) per granule
  size_t offA[GA], offB[2];
#pragma unroll
  for (int gi = 0; gi < GA; ++gi) {
    int beta = gi * 8192 + t * 16;
    int r = ((beta >> 9) << 3) | ((beta >> 4) & 7);
    int c = (beta >> 7) & 3;
    offA[gi] = (size_t)r * K + c * 8;
  }
#pragma unroll
  for (int gj = 0; gj < 2; ++gj) {
    int beta = gj * 8192 + t * 16;
    int r = ((beta >> 9) << 3) | ((beta >> 4) & 7);
    int c = (beta >> 7) & 3;
    offB[gj] = (size_t)r * K + c * 8;
  }

  auto stage = [&](int kt, int gi) {
    f16* bufbase = lds + (kt & 3) * BUF;
    if (gi < GA) {
      gload16(bufbase + gi * 4096 + w * 512, Aorig + offA[gi] + kt * 32);
    } else {
      int gj = gi - GA;
      gload16(bufbase + ATILE + gj * 4096 + w * 512, Borig + offB[gj] + kt * 32);
    }
  };
  const int fragoff = ((l15 >> 3) << 8) + (g << 6) + ((l15 & 7) << 3);
  auto readA = [&](int kt, int mi) -> f16x8 {
    int R0 = wr * (MREP * 16) + mi * 16;
    return *reinterpret_cast<const f16x8*>(lds + (kt & 3) * BUF + R0 * 32 + fragoff);
  };
  auto readB = [&](int kt, int ni) -> f16x8 {
    int R0 = wc * 64 + ni * 16;
    return *reinterpret_cast<const f16x8*>(lds + (kt & 3) * BUF + ATILE + R0 * 32 + fragoff);
  };

  f32x4 acc[MREP][4] = {};

#pragma unroll
  for (int pt = 0; pt < 3; ++pt)
#pragma unroll
    for (int gi = 0; gi < G; ++gi) stage(pt, gi);
  if constexpr (MREP == 8) asm volatile("s_waitcnt vmcnt(8)" ::: "memory");
  else                     asm volatile("s_waitcnt vmcnt(6)" ::: "memory");
  __builtin_amdgcn_s_barrier();

  f16x8 bf[4];
  for (int kt = 0; kt < NT; ++kt) {
    const bool dostage = (kt + 3 < NT);
#pragma unroll
    for (int ph = 0; ph < NPH; ++ph) {
      f16x8 af[4];
#pragma unroll
      for (int mi = 0; mi < 4; ++mi) af[mi] = readA(kt, ph * 4 + mi);
      if (ph == 0) {
#pragma unroll
        for (int ni = 0; ni < 4; ++ni) bf[ni] = readB(kt, ni);
      }
      if (dostage) {
        if constexpr (NPH == 2) {
          stage(kt + 3, ph * 2);
          stage(kt + 3, ph * 2 + 1);
        } else {
          stage(kt + 3, 0);
          stage(kt + 3, 1);
          stage(kt + 3, 2);
        }
      }
      if (ph == NPH - 1) {
        if (kt + 3 < NT) {
          if constexpr (MREP == 8) asm volatile("s_waitcnt vmcnt(8)" ::: "memory");
          else                     asm volatile("s_waitcnt vmcnt(6)" ::: "memory");
        } else if (kt + 2 < NT) {
          if constexpr (MREP == 8) asm volatile("s_waitcnt vmcnt(4)" ::: "memory");
          else                     asm volatile("s_waitcnt vmcnt(3)" ::: "memory");
        } else if (kt + 1 < NT) {
          asm volatile("s_waitcnt vmcnt(0)" ::: "memory");
        }
      }
      __builtin_amdgcn_s_barrier();
      asm volatile("s_waitcnt lgkmcnt(0)" ::: "memory");
      __builtin_amdgcn_s_setprio(1);
#pragma unroll
      for (int mi = 0; mi < 4; ++mi)
#pragma unroll
        for (int ni = 0; ni < 4; ++ni)
          acc[ph * 4 + mi][ni] =
              __builtin_amdgcn_mfma_f32_16x16x32_f16(af[mi], bf[ni], acc[ph * 4 + mi][ni], 0, 0, 0);
      __builtin_amdgcn_s_setprio(0);
      __builtin_amdgcn_s_barrier();
    }
  }

#pragma unroll
  for (int mi = 0; mi < MREP; ++mi) {
    int m0 = mb * BM + wr * (MREP * 16) + mi * 16 + 4 * g;
#pragma unroll
    for (int ni = 0; ni < 4; ++ni) {
      int n = nb * 256 + wc * 64 + ni * 16 + l15;
#pragma unroll
      for (int r = 0; r < 4; ++r) {
        int mm = m0 + r;
        float val = acc[mi][ni][r];
        if (MODE == 0) {
          int b = mm >> 11, s = mm & (NS - 1);
          if (n < 2048) {
            int h = n >> 7, d = n & 127;
            q_out[(((size_t)(b * N_H + h)) * NS + s) * N_HD + d] = (f16)val;
          } else if (n < 2560) {
            int n2 = n - 2048, kvh = n2 >> 7, d = n2 & 127;
            k_out[(((size_t)(b * N_KV + kvh)) * NS + s) * N_HD + d] = (f16)val;
          } else {
            int n3 = n - 2560, kvh = n3 >> 7, d = n3 & 127;
            v_out[(((size_t)(b * N_KV + kvh)) * NS + s) * N_HD + d] = (f16)val;
          }
        } else {
          f_out[(size_t)mm * NHID + n] = val + bias[n];
        }
      }
    }
  }
}

// ---------------- V transpose: [B*NKV][S][HD] -> [B*NKV][HD][S] ----------------
__global__ __launch_bounds__(256) void transpose_v(const f16* __restrict__ V,
                                                   f16* __restrict__ Vt) {
  __shared__ f16 tt[64][72];
  int s0 = blockIdx.x * 64, d0 = blockIdx.y * 64, bk = blockIdx.z;
  const f16* Vp = V + (size_t)bk * NS * N_HD;
  f16* Vtp = Vt + (size_t)bk * N_HD * NS;
  int tid = threadIdx.x;
#pragma unroll
  for (int it = 0; it < 2; ++it) {
    int c = it * 256 + tid;
    int sr = c >> 3, dc = (c & 7) * 8;
    f16x8 v = *reinterpret_cast<const f16x8*>(Vp + (size_t)(s0 + sr) * N_HD + d0 + dc);
#pragma unroll
    for (int j = 0; j < 8; ++j) tt[dc + j][sr] = v[j];
  }
  __syncthreads();
#pragma unroll
  for (int it = 0; it < 2; ++it) {
    int c = it * 256 + tid;
    int dr = c >> 3, sc = (c & 7) * 8;
    f16x8 o;
#pragma unroll
    for (int j = 0; j < 8; ++j) o[j] = tt[dr][sc + j];
    *reinterpret_cast<f16x8*>(Vtp + (size_t)(d0 + dr) * NS + s0 + sc) = o;
  }
}

// ---------------- causal GQA flash attention (fused paired q-tiles) ----------------
// Block pi handles q-tiles {pi, 31-pi}; ONE kf/vf LDS read feeds both tiles'
// MFMAs (halves DS traffic). XCD swizzle: each XCD owns one (b,kvh) group so
// K/V (1MB) is L2-resident. exp2-domain softmax, always-rescale.
__device__ __forceinline__ void stage_kv(const f16* __restrict__ Kp,
                                         const f16* __restrict__ Vp,
                                         f16* Kl, f16* Vl, int kt, int w, int l) {
#pragma unroll
  for (int it = 0; it < 4; ++it) {
    int cb = (it * 4 + w) * 64;
    int c = cb + l;
    int krow = c >> 4, pch = c & 15;
    int sch = (pch & 8) | ((pch ^ krow) & 7);
    gload16(Kl + cb * 8, Kp + (size_t)(kt * 64 + krow) * N_HD + sch * 8);
  }
#pragma unroll
  for (int it = 0; it < 4; ++it) {
    int cb = (it * 4 + w) * 64;
    int c = cb + l;
    int drow = c >> 3, pch = c & 7;
    int sch = (pch ^ drow) & 7;
    gload16(Vl + cb * 8, Vp + (size_t)drow * NS + kt * 64 + sch * 8);
  }
}

__device__ __forceinline__ void qk_dual(const f16x8* qfA, const f16x8* qfB,
                                        const f16* Kl, f32x4* sA, f32x4* sB,
                                        int g, int l15) {
#pragma unroll
  for (int nt = 0; nt < 4; ++nt) {
    f32x4 zA = {0.f, 0.f, 0.f, 0.f}, zB = {0.f, 0.f, 0.f, 0.f};
#pragma unroll
    for (int ks = 0; ks < 4; ++ks) {
      int kr = nt * 16 + l15;
      int ch = ks * 4 + g;
      int sw = (ch & 8) | ((ch ^ kr) & 7);
      f16x8 kf = *reinterpret_cast<const f16x8*>(Kl + kr * 128 + sw * 8);
      zB = __builtin_amdgcn_mfma_f32_16x16x32_f16(qfB[ks], kf, zB, 0, 0, 0);
      zA = __builtin_amdgcn_mfma_f32_16x16x32_f16(qfA[ks], kf, zA, 0, 0, 0);
    }
    sA[nt] = zA; sB[nt] = zB;
  }
}

__device__ __forceinline__ void qk_single(const f16x8* qf, const f16* Kl, f32x4* sB,
                                          int g, int l15) {
#pragma unroll
  for (int nt = 0; nt < 4; ++nt) {
    f32x4 z = {0.f, 0.f, 0.f, 0.f};
#pragma unroll
    for (int ks = 0; ks < 4; ++ks) {
      int kr = nt * 16 + l15;
      int ch = ks * 4 + g;
      int sw = (ch & 8) | ((ch ^ kr) & 7);
      f16x8 kf = *reinterpret_cast<const f16x8*>(Kl + kr * 128 + sw * 8);
      z = __builtin_amdgcn_mfma_f32_16x16x32_f16(qf[ks], kf, z, 0, 0, 0);
    }
    sB[nt] = z;
  }
}

// softmax update + P write (exp2 domain; Q pre-scaled by log2e)
__device__ __forceinline__ void sm_update(const f32x4* sacc, float* mrow, float* lrow,
                                          f32x4* oacc, f16* Pw, int q0, int k0,
                                          int g, int l15, bool diag) {
  float p[4][4];
#pragma unroll
  for (int r = 0; r < 4; ++r) {
    int qg = q0 + r;
    float m = -3.0e38f;
#pragma unroll
    for (int nt = 0; nt < 4; ++nt) {
      float sv = sacc[nt][r];
      if (diag) {
        int kg = k0 + nt * 16 + l15;
        if (kg > qg) sv = -3.0e38f;
      }
      p[nt][r] = sv;
      m = fmaxf(m, sv);
    }
#pragma unroll
    for (int off = 8; off >= 1; off >>= 1) m = fmaxf(m, __shfl_xor(m, off));
    float m2 = fmaxf(mrow[r], m);
    float alpha = __builtin_amdgcn_exp2f(mrow[r] - m2);
    mrow[r] = m2;
    float rs = 0.f;
#pragma unroll
    for (int nt = 0; nt < 4; ++nt) {
      float pv = __builtin_amdgcn_exp2f(p[nt][r] - m2);
      p[nt][r] = pv;
      rs += pv;
    }
#pragma unroll
    for (int off = 8; off >= 1; off >>= 1) rs += __shfl_xor(rs, off);
    lrow[r] = lrow[r] * alpha + rs;
#pragma unroll
    for (int dt = 0; dt < 8; ++dt) oacc[dt][r] *= alpha;
  }
#pragma unroll
  for (int nt = 0; nt < 4; ++nt)
#pragma unroll
    for (int r = 0; r < 4; ++r) {
      int ql = 4 * g + r;
      int kp = nt * 16 + l15;
      int ch = kp >> 3;
      int idx = ql * 64 + (ch ^ (ql & 7)) * 8 + (kp & 7);
      Pw[idx] = (f16)p[nt][r];
    }
}

__device__ __forceinline__ void pv_dual(const f16* Vl, const f16* PwA, const f16* PwB,
                                        f32x4* oA, f32x4* oB, int g, int l15) {
  f16x8 paA[2], paB[2];
#pragma unroll
  for (int ks2 = 0; ks2 < 2; ++ks2) {
    int ch = ks2 * 4 + g;
    paB[ks2] = *reinterpret_cast<const f16x8*>(&PwB[l15 * 64 + (ch ^ (l15 & 7)) * 8]);
    paA[ks2] = *reinterpret_cast<const f16x8*>(&PwA[l15 * 64 + (ch ^ (l15 & 7)) * 8]);
  }
#pragma unroll
  for (int dt = 0; dt < 8; ++dt)
#pragma unroll
    for (int ks2 = 0; ks2 < 2; ++ks2) {
      int d = dt * 16 + l15;
      int ch = ks2 * 4 + g;
      f16x8 vf = *reinterpret_cast<const f16x8*>(Vl + d * 64 + (ch ^ (d & 7)) * 8);
      oB[dt] = __builtin_amdgcn_mfma_f32_16x16x32_f16(paB[ks2], vf, oB[dt], 0, 0, 0);
      oA[dt] = __builtin_amdgcn_mfma_f32_16x16x32_f16(paA[ks2], vf, oA[dt], 0, 0, 0);
    }
}

__device__ __forceinline__ void pv_single(const f16* Vl, const f16* PwB,
                                          f32x4* oB, int g, int l15) {
  f16x8 pa[2];
#pragma unroll
  for (int ks2 = 0; ks2 < 2; ++ks2) {
    int ch = ks2 * 4 + g;
    pa[ks2] = *reinterpret_cast<const f16x8*>(&PwB[l15 * 64 + (ch ^ (l15 & 7)) * 8]);
  }
#pragma unroll
  for (int dt = 0; dt < 8; ++dt)
#pragma unroll
    for (int ks2 = 0; ks2 < 2; ++ks2) {
      int d = dt * 16 + l15;
      int ch = ks2 * 4 + g;
      f16x8 vf = *reinterpret_cast<const f16x8*>(Vl + d * 64 + (ch ^ (d & 7)) * 8);
      oB[dt] = __builtin_amdgcn_mfma_f32_16x16x32_f16(pa[ks2], vf, oB[dt], 0, 0, 0);
    }
}

__global__ __launch_bounds__(256, 2) void attn_kernel(
    const f16* __restrict__ Q, const f16* __restrict__ K,
    const f16* __restrict__ Vt, f16* __restrict__ O) {
  __shared__ f16 Klds[2][64 * 128];    // 32 KB
  __shared__ f16 Vlds[2][128 * 64];    // 32 KB
  __shared__ f16 Plds[4][2][16 * 64];  // 16 KB (per wave x {A,B})
  const int t = threadIdx.x, l = t & 63, w = t >> 6;
  const int g = l >> 4, l15 = l & 15;
  // XCD swizzle: XCD x owns (b,kvh) group x; local = {j=h within group, pi}
  const int orig = blockIdx.x;                 // 0..511
  const int x = orig & 7, loc = orig >> 3;     // loc 0..63
  const int b = x >> 2, kvh = x & 3;
  const int h = kvh * 4 + (loc & 3);
  const int pi = loc >> 2;                     // 0..15
  const int qtA = pi, qtB = 31 - pi;
  const f16* Qp = Q + ((size_t)(b * N_H + h)) * NS * N_HD;
  const f16* Kp = K + ((size_t)(b * N_KV + kvh)) * NS * N_HD;
  const f16* Vp = Vt + ((size_t)(b * N_KV + kvh)) * N_HD * NS;

  // Q fragments in registers for both tiles, pre-scaled by log2(e)
  const f16 l2e = (f16)1.44269504f;
  f16x8 qfA[4], qfB[4];
  const int qrA = qtA * 64 + w * 16 + l15;
  const int qrB = qtB * 64 + w * 16 + l15;
#pragma unroll
  for (int ks = 0; ks < 4; ++ks) {
    qfA[ks] = *reinterpret_cast<const f16x8*>(Qp + (size_t)qrA * N_HD + ks * 32 + g * 8);
    qfB[ks] = *reinterpret_cast<const f16x8*>(Qp + (size_t)qrB * N_HD + ks * 32 + g * 8);
#pragma unroll
    for (int j = 0; j < 8; ++j) { qfA[ks][j] *= l2e; qfB[ks][j] *= l2e; }
  }

  f32x4 oA[8] = {}, oB[8] = {};
  float mA[4], lAr[4], mB[4], lBr[4];
#pragma unroll
  for (int r = 0; r < 4; ++r) {
    mA[r] = -3.0e38f; lAr[r] = 0.f;
    mB[r] = -3.0e38f; lBr[r] = 0.f;
  }
  const int q0A = qtA * 64 + w * 16 + 4 * g;
  const int q0B = qtB * 64 + w * 16 + 4 * g;
  f16* PA = &Plds[w][0][0];
  f16* PB = &Plds[w][1][0];

  const int nkt = qtB + 1;
  stage_kv(Kp, Vp, Klds[0], Vlds[0], 0, w, l);
  asm volatile("s_waitcnt vmcnt(0)" ::: "memory");
  __syncthreads();
  int cur = 0;
  for (int kt = 0; kt < nkt; ++kt) {
    if (kt + 1 < nkt)
      stage_kv(Kp, Vp, Klds[cur ^ 1], Vlds[cur ^ 1], kt + 1, w, l);
    const bool doA = (kt <= qtA);
    f32x4 sA[4], sB[4];
    __builtin_amdgcn_s_setprio(1);
    if (doA) qk_dual(qfA, qfB, Klds[cur], sA, sB, g, l15);
    else     qk_single(qfB, Klds[cur], sB, g, l15);
    __builtin_amdgcn_s_setprio(0);
    sm_update(sB, mB, lBr, oB, PB, q0B, kt * 64, g, l15, kt == qtB);
    if (doA)
      sm_update(sA, mA, lAr, oA, PA, q0A, kt * 64, g, l15, kt == qtA);
    asm volatile("s_waitcnt lgkmcnt(0)" ::: "memory");
    __builtin_amdgcn_sched_barrier(0);
    __builtin_amdgcn_s_setprio(1);
    if (doA) pv_dual(Vlds[cur], PA, PB, oA, oB, g, l15);
    else     pv_single(Vlds[cur], PB, oB, g, l15);
    __builtin_amdgcn_s_setprio(0);
    asm volatile("s_waitcnt vmcnt(0)" ::: "memory");
    __syncthreads();
    cur ^= 1;
  }

  // normalize + write attn_out [B*S][NH*HD] fp16
#pragma unroll
  for (int r = 0; r < 4; ++r) {
    float invB = 1.0f / lBr[r];
    f16* orowB = O + (size_t)(b * NS + q0B + r) * NHID + h * N_HD;
#pragma unroll
    for (int dt = 0; dt < 8; ++dt) orowB[dt * 16 + l15] = (f16)(oB[dt][r] * invB);
    float invA = 1.0f / lAr[r];
    f16* orowA = O + (size_t)(b * NS + q0A + r) * NHID + h * N_HD;
#pragma unroll
    for (int dt = 0; dt < 8; ++dt) orowA[dt * 16 + l15] = (f16)(oA[dt][r] * invA);
  }
}

extern "C" void kernel_launch(void* const* d_in, const int* in_sizes, int n_in,
                              void* d_out, int out_size, void* d_ws, size_t ws_size,
                              hipStream_t stream) {
  const float* hs = (const float*)d_in[0];
  const float* Wq = (const float*)d_in[1];
  const float* Wk = (const float*)d_in[2];
  const float* Wv = (const float*)d_in[3];
  const float* Wo = (const float*)d_in[4];
  const float* bo = (const float*)d_in[5];
  float* out = (float*)d_out;

  char* ws = (char*)d_ws;
  f16* Xh   = (f16*)(ws);
  f16* Wqkv = (f16*)(ws + 16777216);
  f16* Woh  = (f16*)(ws + 29360128);
  f16* Qb   = (f16*)(ws + 37748736);
  f16* Kb   = (f16*)(ws + 54525952);
  f16* Vb   = (f16*)(ws + 58720256);
  f16* Vtb  = (f16*)(ws + 62914560);
  f16* Ob   = Xh;  // X dead after QKV GEMM; reuse for attention output

  cvt_kernel<<<8192, 256, 0, stream>>>(hs, Xh, 2097152);
  cvt3_kernel<<<6144, 256, 0, stream>>>(Wq, 1048576, Wk, 262144, Wv, 262144, Wqkv);
  cvt_kernel<<<4096, 256, 0, stream>>>(Wo, Woh, 1048576);

  gemm8<8, 0><<<192, 512, 0, stream>>>(Xh, Wqkv, 2048, Qb, Kb, Vb, nullptr, nullptr);
  transpose_v<<<dim3(32, 2, 8), 256, 0, stream>>>(Vb, Vtb);
  attn_kernel<<<512, 256, 0, stream>>>(Qb, Kb, Vtb, Ob);
  gemm8<4, 1><<<256, 512, 0, stream>>>(Ob, Woh, 2048, nullptr, nullptr, nullptr, out, bo);
}

// Round 5
// 216.109 us; speedup vs baseline: 1.1809x; 1.1809x over previous
//
#include <hip/hip_runtime.h>

typedef _Float16 f16;
typedef __attribute__((ext_vector_type(4))) _Float16 f16x4;
typedef __attribute__((ext_vector_type(8))) _Float16 f16x8;
typedef __attribute__((ext_vector_type(4))) float f32x4;

#define NB 2
#define NS 2048
#define NHID 2048
#define N_H 16
#define N_KV 4
#define N_HD 128

__device__ __forceinline__ void gload16(void* lds, const void* g) {
  __builtin_amdgcn_global_load_lds(
      (const __attribute__((address_space(1))) unsigned int*)g,
      (__attribute__((address_space(3))) unsigned int*)lds, 16, 0, 0);
}

// ---------------- fused f32 -> f16 convert for all 5 inputs ----------------
__global__ __launch_bounds__(256) void cvt_all(
    const float* __restrict__ hs, const float* __restrict__ Wq,
    const float* __restrict__ Wk, const float* __restrict__ Wv,
    const float* __restrict__ Wo, f16* __restrict__ Xh,
    f16* __restrict__ Wqkv, f16* __restrict__ Woh) {
  int i = blockIdx.x * 256 + threadIdx.x;  // float4 index, total 4718592
  const float* src;
  f16* dst;
  int j;
  if (i < 2097152)      { src = hs; dst = Xh;             j = i; }
  else if (i < 3145728) { src = Wq; dst = Wqkv;           j = i - 2097152; }
  else if (i < 3407872) { src = Wk; dst = Wqkv + 4194304; j = i - 3145728; }
  else if (i < 3670016) { src = Wv; dst = Wqkv + 5242880; j = i - 3407872; }
  else                  { src = Wo; dst = Woh;            j = i - 3670016; }
  const float4 v = reinterpret_cast<const float4*>(src)[j];
  f16x4 o = {(f16)v.x, (f16)v.y, (f16)v.z, (f16)v.w};
  reinterpret_cast<f16x4*>(dst)[j] = o;
}

// ---------------- QKV GEMM: BM=256 x BN=192 x BK=64, grid 256 = 1/CU ----------------
// 8 waves (2M x 4N; wave = 128 rows x 48 cols), 2-buffer ring, stage(kt+1)
// before compute(kt). Granule-permuted LDS (slot s <-> row ((s>>5)<<3)|(s&7),
// col-chunk (s>>3)&3) so frag ds_read_b128 is at the 8-cycle floor; staging
// keeps LDS dest linear (wave-uniform base + lane*16B) and permutes the
// per-lane GLOBAL source. Scatters C into Q/K/V fp16 [B,H,S,D].
__global__ __launch_bounds__(512, 2) void gemm_qkv(
    const f16* __restrict__ A, const f16* __restrict__ Bm,
    f16* __restrict__ q_out, f16* __restrict__ k_out, f16* __restrict__ v_out) {
  constexpr int K = 2048;
  // per buffer (f16): [A0 8192][A1 8192][B0 6144][B1 6144] = 28672 (56 KB)
  __shared__ f16 lds[2][28672];
  const int t = threadIdx.x;
  const int l = t & 63, w = t >> 6;
  const int g = l >> 4, l15 = l & 15;
  const int wr = w >> 2, wc = w & 3;
  // XCD-rectangle swizzle over 16mb x 16nb
  const int orig = blockIdx.x;
  const int x = orig & 7, loc = orig >> 3;         // loc 0..31
  const int mb = (x & 3) * 4 + (loc & 3);
  const int nb = (x >> 2) * 8 + (loc >> 2);
  const f16* Ab = A + (size_t)(mb * 256) * K;
  const f16* Bb = Bm + (size_t)(nb * 192) * K;

  // thread -> (row, col-chunk) inside an 8KB granule
  const int rA = ((t >> 5) << 3) | (t & 7);
  const int cA = (t >> 3) & 3;
  const int t2 = t & 255;
  const int rB2 = ((t2 >> 5) << 3) | (t2 & 7);
  const int cB2 = (t2 >> 3) & 3;

  auto stage = [&](int kt) {
    f16* buf = lds[kt & 1];
#pragma unroll
    for (int h = 0; h < 2; ++h) {
#pragma unroll
      for (int gi = 0; gi < 2; ++gi)
        gload16(buf + h * 8192 + gi * 4096 + w * 512,
                Ab + (size_t)(gi * 128 + rA) * K + kt * 64 + h * 32 + cA * 8);
      gload16(buf + 16384 + h * 6144 + w * 512,
              Bb + (size_t)rA * K + kt * 64 + h * 32 + cA * 8);
      if (t < 256)
        gload16(buf + 16384 + h * 6144 + 4096 + w * 512,
                Bb + (size_t)(128 + rB2) * K + kt * 64 + h * 32 + cB2 * 8);
    }
  };
  const int fragoff = ((l15 >> 3) << 8) + (g << 6) + ((l15 & 7) << 3);

  f32x4 acc[8][3] = {};

  stage(0);
  asm volatile("s_waitcnt vmcnt(0)" ::: "memory");
  __builtin_amdgcn_s_barrier();

  for (int kt = 0; kt < 32; ++kt) {
    if (kt + 1 < 32) stage(kt + 1);
    const f16* buf = lds[kt & 1];
#pragma unroll
    for (int h = 0; h < 2; ++h) {
      f16x8 af[8], bf[3];
#pragma unroll
      for (int mi = 0; mi < 8; ++mi)
        af[mi] = *reinterpret_cast<const f16x8*>(buf + h * 8192 + (wr * 128 + mi * 16) * 32 + fragoff);
#pragma unroll
      for (int ni = 0; ni < 3; ++ni)
        bf[ni] = *reinterpret_cast<const f16x8*>(buf + 16384 + h * 6144 + (wc * 48 + ni * 16) * 32 + fragoff);
      __builtin_amdgcn_s_setprio(1);
#pragma unroll
      for (int mi = 0; mi < 8; ++mi)
#pragma unroll
        for (int ni = 0; ni < 3; ++ni)
          acc[mi][ni] = __builtin_amdgcn_mfma_f32_16x16x32_f16(af[mi], bf[ni], acc[mi][ni], 0, 0, 0);
      __builtin_amdgcn_s_setprio(0);
    }
    if (kt + 1 < 32) asm volatile("s_waitcnt vmcnt(0)" ::: "memory");
    __builtin_amdgcn_s_barrier();
  }

  // scatter epilogue: D[row=4g+r][col=l15] per fragment
#pragma unroll
  for (int mi = 0; mi < 8; ++mi) {
    int m0 = mb * 256 + wr * 128 + mi * 16 + 4 * g;
#pragma unroll
    for (int ni = 0; ni < 3; ++ni) {
      int n = nb * 192 + wc * 48 + ni * 16 + l15;
#pragma unroll
      for (int r = 0; r < 4; ++r) {
        int mm = m0 + r;
        float val = acc[mi][ni][r];
        int b = mm >> 11, s = mm & (NS - 1);
        if (n < 2048) {
          int h = n >> 7, d = n & 127;
          q_out[(((size_t)(b * N_H + h)) * NS + s) * N_HD + d] = (f16)val;
        } else if (n < 2560) {
          int n2 = n - 2048, kvh = n2 >> 7, d = n2 & 127;
          k_out[(((size_t)(b * N_KV + kvh)) * NS + s) * N_HD + d] = (f16)val;
        } else {
          int n3 = n - 2560, kvh = n3 >> 7, d = n3 & 127;
          v_out[(((size_t)(b * N_KV + kvh)) * NS + s) * N_HD + d] = (f16)val;
        }
      }
    }
  }
}

// ---------------- outproj GEMM (from R4, MODE 1 only) ----------------
template <int MREP, int MODE>
__global__ __launch_bounds__(512, 2) void gemm8(
    const f16* __restrict__ A, const f16* __restrict__ Bm, const int K,
    float* __restrict__ f_out, const float* __restrict__ bias) {
  constexpr int BM = MREP * 32;
  constexpr int GA = BM / 128;
  constexpr int G = GA + 2;
  constexpr int NPH = (MREP == 8) ? 2 : 1;
  constexpr int ATILE = BM * 32;
  constexpr int BTILE = 256 * 32;
  constexpr int BUF = ATILE + BTILE;
  __shared__ f16 lds[4 * BUF];

  const int t = threadIdx.x;
  const int l = t & 63, w = t >> 6;
  const int g = l >> 4, l15 = l & 15;
  const int wr = w >> 2, wc = w & 3;
  const int orig = blockIdx.x;
  const int x = orig & 7, loc = orig >> 3;
  int mb, nb;
  mb = (x & 3) * 8 + (loc & 7); nb = (x >> 2) * 4 + (loc >> 3);
  const int NT = K >> 5;

  const f16* Aorig = A + (size_t)(mb * BM) * K;
  const f16* Borig = Bm + (size_t)(nb * 256) * K;

  size_t offA[GA], offB[2];
#pragma unroll
  for (int gi = 0; gi < GA; ++gi) {
    int beta = gi * 8192 + t * 16;
    int r = ((beta >> 9) << 3) | ((beta >> 4) & 7);
    int c = (beta >> 7) & 3;
    offA[gi] = (size_t)r * K + c * 8;
  }
#pragma unroll
  for (int gj = 0; gj < 2; ++gj) {
    int beta = gj * 8192 + t * 16;
    int r = ((beta >> 9) << 3) | ((beta >> 4) & 7);
    int c = (beta >> 7) & 3;
    offB[gj] = (size_t)r * K + c * 8;
  }

  auto stage = [&](int kt, int gi) {
    f16* bufbase = lds + (kt & 3) * BUF;
    if (gi < GA) {
      gload16(bufbase + gi * 4096 + w * 512, Aorig + offA[gi] + kt * 32);
    } else {
      int gj = gi - GA;
      gload16(bufbase + ATILE + gj * 4096 + w * 512, Borig + offB[gj] + kt * 32);
    }
  };
  const int fragoff = ((l15 >> 3) << 8) + (g << 6) + ((l15 & 7) << 3);
  auto readA = [&](int kt, int mi) -> f16x8 {
    int R0 = wr * (MREP * 16) + mi * 16;
    return *reinterpret_cast<const f16x8*>(lds + (kt & 3) * BUF + R0 * 32 + fragoff);
  };
  auto readB = [&](int kt, int ni) -> f16x8 {
    int R0 = wc * 64 + ni * 16;
    return *reinterpret_cast<const f16x8*>(lds + (kt & 3) * BUF + ATILE + R0 * 32 + fragoff);
  };

  f32x4 acc[MREP][4] = {};

#pragma unroll
  for (int pt = 0; pt < 3; ++pt)
#pragma unroll
    for (int gi = 0; gi < G; ++gi) stage(pt, gi);
  asm volatile("s_waitcnt vmcnt(6)" ::: "memory");
  __builtin_amdgcn_s_barrier();

  f16x8 bf[4];
  for (int kt = 0; kt < NT; ++kt) {
    const bool dostage = (kt + 3 < NT);
#pragma unroll
    for (int ph = 0; ph < NPH; ++ph) {
      f16x8 af[4];
#pragma unroll
      for (int mi = 0; mi < 4; ++mi) af[mi] = readA(kt, ph * 4 + mi);
      if (ph == 0) {
#pragma unroll
        for (int ni = 0; ni < 4; ++ni) bf[ni] = readB(kt, ni);
      }
      if (dostage) {
        stage(kt + 3, 0);
        stage(kt + 3, 1);
        stage(kt + 3, 2);
      }
      if (ph == NPH - 1) {
        if (kt + 3 < NT)      asm volatile("s_waitcnt vmcnt(6)" ::: "memory");
        else if (kt + 2 < NT) asm volatile("s_waitcnt vmcnt(3)" ::: "memory");
        else if (kt + 1 < NT) asm volatile("s_waitcnt vmcnt(0)" ::: "memory");
      }
      __builtin_amdgcn_s_barrier();
      asm volatile("s_waitcnt lgkmcnt(0)" ::: "memory");
      __builtin_amdgcn_s_setprio(1);
#pragma unroll
      for (int mi = 0; mi < 4; ++mi)
#pragma unroll
        for (int ni = 0; ni < 4; ++ni)
          acc[ph * 4 + mi][ni] =
              __builtin_amdgcn_mfma_f32_16x16x32_f16(af[mi], bf[ni], acc[ph * 4 + mi][ni], 0, 0, 0);
      __builtin_amdgcn_s_setprio(0);
      __builtin_amdgcn_s_barrier();
    }
  }

#pragma unroll
  for (int mi = 0; mi < MREP; ++mi) {
    int m0 = mb * BM + wr * (MREP * 16) + mi * 16 + 4 * g;
#pragma unroll
    for (int ni = 0; ni < 4; ++ni) {
      int n = nb * 256 + wc * 64 + ni * 16 + l15;
#pragma unroll
      for (int r = 0; r < 4; ++r) {
        f_out[(size_t)(m0 + r) * NHID + n] = acc[mi][ni][r] + bias[n];
      }
    }
  }
}

// ---------------- V transpose: [B*NKV][S][HD] -> [B*NKV][HD][S] ----------------
__global__ __launch_bounds__(256) void transpose_v(const f16* __restrict__ V,
                                                   f16* __restrict__ Vt) {
  __shared__ f16 tt[64][72];
  int s0 = blockIdx.x * 64, d0 = blockIdx.y * 64, bk = blockIdx.z;
  const f16* Vp = V + (size_t)bk * NS * N_HD;
  f16* Vtp = Vt + (size_t)bk * N_HD * NS;
  int tid = threadIdx.x;
#pragma unroll
  for (int it = 0; it < 2; ++it) {
    int c = it * 256 + tid;
    int sr = c >> 3, dc = (c & 7) * 8;
    f16x8 v = *reinterpret_cast<const f16x8*>(Vp + (size_t)(s0 + sr) * N_HD + d0 + dc);
#pragma unroll
    for (int j = 0; j < 8; ++j) tt[dc + j][sr] = v[j];
  }
  __syncthreads();
#pragma unroll
  for (int it = 0; it < 2; ++it) {
    int c = it * 256 + tid;
    int dr = c >> 3, sc = (c & 7) * 8;
    f16x8 o;
#pragma unroll
    for (int j = 0; j < 8; ++j) o[j] = tt[dr][sc + j];
    *reinterpret_cast<f16x8*>(Vtp + (size_t)(d0 + dr) * NS + s0 + sc) = o;
  }
}

// ---------------- causal GQA flash attention (R2 structure) ----------------
// Paired q-tiles {pi, 31-pi} share one K/V staging; double-buffered,
// stage(kt+1) before compute(kt). exp2-domain softmax (log2e folded into Q);
// row-sum via ones-MFMA reusing pa fragments (replaces shfl sum-reduce).
__device__ __forceinline__ void stage_kv(const f16* __restrict__ Kp,
                                         const f16* __restrict__ Vp,
                                         f16* Kl, f16* Vl, int kt, int w, int l) {
#pragma unroll
  for (int it = 0; it < 4; ++it) {
    int cb = (it * 4 + w) * 64;
    int c = cb + l;
    int krow = c >> 4, pch = c & 15;
    int sch = (pch & 8) | ((pch ^ krow) & 7);
    gload16(Kl + cb * 8, Kp + (size_t)(kt * 64 + krow) * N_HD + sch * 8);
  }
#pragma unroll
  for (int it = 0; it < 4; ++it) {
    int cb = (it * 4 + w) * 64;
    int c = cb + l;
    int drow = c >> 3, pch = c & 7;
    int sch = (pch ^ drow) & 7;
    gload16(Vl + cb * 8, Vp + (size_t)drow * NS + kt * 64 + sch * 8);
  }
}

__device__ __forceinline__ void attn_step(
    const f16x8* qf, f32x4* oacc, float* mrow, float* lrow, int q0, int kt,
    const f16* Kl, const f16* Vl, f16* Pw, int g, int l15, bool diag) {
  // S = Q K^T (Q pre-scaled by log2e): acc D[q=4g+r][kpos=l15+16nt]
  f32x4 sacc[4];
#pragma unroll
  for (int nt = 0; nt < 4; ++nt) {
    f32x4 z = {0.f, 0.f, 0.f, 0.f};
#pragma unroll
    for (int ks = 0; ks < 4; ++ks) {
      int kr = nt * 16 + l15;
      int ch = ks * 4 + g;
      int sw = (ch & 8) | ((ch ^ kr) & 7);
      f16x8 kf = *reinterpret_cast<const f16x8*>(Kl + kr * 128 + sw * 8);
      z = __builtin_amdgcn_mfma_f32_16x16x32_f16(qf[ks], kf, z, 0, 0, 0);
    }
    sacc[nt] = z;
  }

  // causal mask + wave-parallel max; exp2; scale old state
  float p[4][4];
#pragma unroll
  for (int r = 0; r < 4; ++r) {
    int qg = q0 + r;
    float m = -3.0e38f;
#pragma unroll
    for (int nt = 0; nt < 4; ++nt) {
      float sv = sacc[nt][r];
      if (diag) {
        int kg = kt * 64 + nt * 16 + l15;
        if (kg > qg) sv = -3.0e38f;
      }
      p[nt][r] = sv;
      m = fmaxf(m, sv);
    }
#pragma unroll
    for (int off = 8; off >= 1; off >>= 1) m = fmaxf(m, __shfl_xor(m, off));
    float m2 = fmaxf(mrow[r], m);
    float alpha = __builtin_amdgcn_exp2f(mrow[r] - m2);
    mrow[r] = m2;
    lrow[r] *= alpha;
#pragma unroll
    for (int nt = 0; nt < 4; ++nt)
      p[nt][r] = __builtin_amdgcn_exp2f(p[nt][r] - m2);
#pragma unroll
    for (int dt = 0; dt < 8; ++dt) oacc[dt][r] *= alpha;
  }

  // P -> per-wave LDS (swizzled), then read back as A-op fragments
#pragma unroll
  for (int nt = 0; nt < 4; ++nt)
#pragma unroll
    for (int r = 0; r < 4; ++r) {
      int ql = 4 * g + r;
      int kp = nt * 16 + l15;
      int ch = kp >> 3;
      int idx = ql * 64 + (ch ^ (ql & 7)) * 8 + (kp & 7);
      Pw[idx] = (f16)p[nt][r];
    }
  asm volatile("s_waitcnt lgkmcnt(0)" ::: "memory");
  __builtin_amdgcn_sched_barrier(0);

  f16x8 pa[2];
#pragma unroll
  for (int ks2 = 0; ks2 < 2; ++ks2) {
    int ch = ks2 * 4 + g;
    pa[ks2] = *reinterpret_cast<const f16x8*>(&Pw[l15 * 64 + (ch ^ (l15 & 7)) * 8]);
  }
  // row-sum via ones-MFMA (all lanes get Sum_k P[row,k] in lacc[r])
  const f16x8 ones = {(f16)1.f, (f16)1.f, (f16)1.f, (f16)1.f,
                      (f16)1.f, (f16)1.f, (f16)1.f, (f16)1.f};
  f32x4 lacc = {0.f, 0.f, 0.f, 0.f};
#pragma unroll
  for (int ks2 = 0; ks2 < 2; ++ks2)
    lacc = __builtin_amdgcn_mfma_f32_16x16x32_f16(pa[ks2], ones, lacc, 0, 0, 0);
  // O += P V : B-op = V[k][d] from Vl[d][k]
#pragma unroll
  for (int dt = 0; dt < 8; ++dt)
#pragma unroll
    for (int ks2 = 0; ks2 < 2; ++ks2) {
      int d = dt * 16 + l15;
      int ch = ks2 * 4 + g;
      f16x8 vf = *reinterpret_cast<const f16x8*>(Vl + d * 64 + (ch ^ (d & 7)) * 8);
      oacc[dt] = __builtin_amdgcn_mfma_f32_16x16x32_f16(pa[ks2], vf, oacc[dt], 0, 0, 0);
    }
#pragma unroll
  for (int r = 0; r < 4; ++r) lrow[r] += lacc[r];
}

__global__ __launch_bounds__(256, 2) void attn_kernel(
    const f16* __restrict__ Q, const f16* __restrict__ K,
    const f16* __restrict__ Vt, f16* __restrict__ O) {
  __shared__ f16 Klds[2][64 * 128];
  __shared__ f16 Vlds[2][128 * 64];
  __shared__ f16 Plds[4][16 * 64];
  const int t = threadIdx.x, l = t & 63, w = t >> 6;
  const int g = l >> 4, l15 = l & 15;
  // XCD swizzle: XCD x owns (b,kvh) group so K/V stays L2-resident
  const int orig = blockIdx.x;               // 0..511
  const int x = orig & 7, loc = orig >> 3;   // loc 0..63
  const int b = x >> 2, kvh = x & 3;
  const int h = kvh * 4 + (loc & 3);
  const int pi = loc >> 2;                   // 0..15
  const int qtA = pi, qtB = 31 - pi;
  const f16* Qp = Q + ((size_t)(b * N_H + h)) * NS * N_HD;
  const f16* Kp = K + ((size_t)(b * N_KV + kvh)) * NS * N_HD;
  const f16* Vp = Vt + ((size_t)(b * N_KV + kvh)) * N_HD * NS;

  const f16 l2e = (f16)1.44269504f;
  f16x8 qfA[4], qfB[4];
  const int qrA = qtA * 64 + w * 16 + l15;
  const int qrB = qtB * 64 + w * 16 + l15;
#pragma unroll
  for (int ks = 0; ks < 4; ++ks) {
    qfA[ks] = *reinterpret_cast<const f16x8*>(Qp + (size_t)qrA * N_HD + ks * 32 + g * 8);
    qfB[ks] = *reinterpret_cast<const f16x8*>(Qp + (size_t)qrB * N_HD + ks * 32 + g * 8);
#pragma unroll
    for (int j = 0; j < 8; ++j) { qfA[ks][j] *= l2e; qfB[ks][j] *= l2e; }
  }

  f32x4 oA[8] = {}, oB[8] = {};
  float mA[4], lAr[4], mB[4], lBr[4];
#pragma unroll
  for (int r = 0; r < 4; ++r) {
    mA[r] = -3.0e38f; lAr[r] = 0.f;
    mB[r] = -3.0e38f; lBr[r] = 0.f;
  }
  const int q0A = qtA * 64 + w * 16 + 4 * g;
  const int q0B = qtB * 64 + w * 16 + 4 * g;

  const int nkt = qtB + 1;
  stage_kv(Kp, Vp, Klds[0], Vlds[0], 0, w, l);
  asm volatile("s_waitcnt vmcnt(0)" ::: "memory");
  __syncthreads();
  int cur = 0;
  for (int kt = 0; kt < nkt; ++kt) {
    if (kt + 1 < nkt)
      stage_kv(Kp, Vp, Klds[cur ^ 1], Vlds[cur ^ 1], kt + 1, w, l);
    attn_step(qfB, oB, mB, lBr, q0B, kt, Klds[cur], Vlds[cur], Plds[w], g, l15, kt == qtB);
    if (kt <= qtA)
      attn_step(qfA, oA, mA, lAr, q0A, kt, Klds[cur], Vlds[cur], Plds[w], g, l15, kt == qtA);
    asm volatile("s_waitcnt vmcnt(0)" ::: "memory");
    __syncthreads();
    cur ^= 1;
  }

  // normalize + write attn_out [B*S][NH*HD] fp16
#pragma unroll
  for (int r = 0; r < 4; ++r) {
    float invB = 1.0f / lBr[r];
    f16* orowB = O + (size_t)(b * NS + q0B + r) * NHID + h * N_HD;
#pragma unroll
    for (int dt = 0; dt < 8; ++dt) orowB[dt * 16 + l15] = (f16)(oB[dt][r] * invB);
    float invA = 1.0f / lAr[r];
    f16* orowA = O + (size_t)(b * NS + q0A + r) * NHID + h * N_HD;
#pragma unroll
    for (int dt = 0; dt < 8; ++dt) orowA[dt * 16 + l15] = (f16)(oA[dt][r] * invA);
  }
}

extern "C" void kernel_launch(void* const* d_in, const int* in_sizes, int n_in,
                              void* d_out, int out_size, void* d_ws, size_t ws_size,
                              hipStream_t stream) {
  const float* hs = (const float*)d_in[0];
  const float* Wq = (const float*)d_in[1];
  const float* Wk = (const float*)d_in[2];
  const float* Wv = (const float*)d_in[3];
  const float* Wo = (const float*)d_in[4];
  const float* bo = (const float*)d_in[5];
  float* out = (float*)d_out;

  char* ws = (char*)d_ws;
  f16* Xh   = (f16*)(ws);
  f16* Wqkv = (f16*)(ws + 16777216);
  f16* Woh  = (f16*)(ws + 29360128);
  f16* Qb   = (f16*)(ws + 37748736);
  f16* Kb   = (f16*)(ws + 54525952);
  f16* Vb   = (f16*)(ws + 58720256);
  f16* Vtb  = (f16*)(ws + 62914560);
  f16* Ob   = Xh;  // X dead after QKV GEMM; reuse for attention output

  cvt_all<<<18432, 256, 0, stream>>>(hs, Wq, Wk, Wv, Wo, Xh, Wqkv, Woh);
  gemm_qkv<<<256, 512, 0, stream>>>(Xh, Wqkv, Qb, Kb, Vb);
  transpose_v<<<dim3(32, 2, 8), 256, 0, stream>>>(Vb, Vtb);
  attn_kernel<<<512, 256, 0, stream>>>(Qb, Kb, Vtb, Ob);
  gemm8<4, 1><<<256, 512, 0, stream>>>(Ob, Woh, 2048, out, bo);
}